// Round 1
// baseline (109.301 us; speedup 1.0000x reference)
//
#include <hip/hip_runtime.h>
#include <hip/hip_bf16.h>

// KAN conv: out[b,o,h,w] = sum_{j,k,l,m} phi(x[b,j,h+k,w+l])[m] * coeff[o,j,k,l,m]
// phi = uniform cubic B-spline basis (8 bases, knots = linspace(0,1,12)).
// Strategy: per-(b,h) block, MFMA GEMM M=Cout(64) x N=w(64 pad) x K=4608,
// Cin chunked by 16 with phi staged to LDS as bf16.

typedef short v8s __attribute__((ext_vector_type(8)));
typedef float v4f __attribute__((ext_vector_type(4)));

#define B_N   16
#define CIN   64
#define COUT  64
#define H_IN  64
#define W_IN  64
#define NB    8
#define HO    62
#define WO    62
#define JC    16   // Cin chunk size

__device__ __forceinline__ ushort f2bf(float f) {
    // round-to-nearest-even fp32 -> bf16 (no NaN handling needed here)
    uint xu = __float_as_uint(f);
    uint r = (xu + 0x7fffu + ((xu >> 16) & 1u)) >> 16;
    return (ushort)r;
}

// Rearrange coeff [o][j][k][l][m] f32 -> bt[t=j*9+k*3+l][o][m] bf16 (576 KB)
__global__ void prep_coeff_kernel(const float* __restrict__ coeff, ushort* __restrict__ bt) {
    int n = blockIdx.x * 256 + threadIdx.x;
    if (n >= 576 * COUT * NB) return;
    int m = n & 7;
    int o = (n >> 3) & 63;
    int t = n >> 9;            // j*9 + k*3 + l
    int j = t / 9;
    int r9 = t - j * 9;
    float v = coeff[(((o * CIN + j) * 9 + r9) << 3) + m];
    bt[n] = f2bf(v);
}

template<bool USE_BT>
__global__ __launch_bounds__(256, 3) void kan_conv_kernel(
        const float* __restrict__ x, const ushort* __restrict__ cb,
        const float* __restrict__ coeff_f, float* __restrict__ out) {
    const int h    = blockIdx.x;   // 0..61
    const int b    = blockIdx.y;   // 0..15
    const int tid  = threadIdx.x;
    const int lane = tid & 63;
    const int wv   = tid >> 6;
    const int g    = lane >> 4;    // k-subgroup 0..3
    const int l15  = lane & 15;
    const int obase = (wv >> 1) << 5;  // Cout half: 0 or 32
    const int wbase = (wv & 1) << 5;   // w half:    0 or 32

    // phi_lds[k(3)][j(JC)][w(64)][m(8)] bf16 = 48 KB
    __shared__ __align__(16) ushort phi_lds[3 * JC * W_IN * NB];
    __shared__ uint lut[144];   // tap -> phi base offset | l<<16 | j<<20 | r9<<24

    if (tid < 144) {
        int tap = tid;
        int j  = tap / 9;
        int r9 = tap - j * 9;
        int kt = r9 / 3;
        int lt = r9 - kt * 3;
        lut[tap] = (uint)(((kt * JC + j) * W_IN) * NB) | ((uint)lt << 16)
                 | ((uint)j << 20) | ((uint)r9 << 24);
    }

    v4f acc00 = {0.f, 0.f, 0.f, 0.f};
    v4f acc01 = acc00, acc10 = acc00, acc11 = acc00;
    const int aoff = obase + l15;

    for (int jc = 0; jc < CIN / JC; ++jc) {
        const int j0 = jc * JC;
        __syncthreads();                       // prev GEMM done before overwrite
        // zero-fill phi (only 4 of 8 bases are nonzero per element)
        uint4 z4 = make_uint4(0u, 0u, 0u, 0u);
        #pragma unroll
        for (int it = 0; it < (3 * JC * W_IN) / 256; ++it) {
            int n = it * 256 + tid;
            *reinterpret_cast<uint4*>(&phi_lds[n << 3]) = z4;
        }
        __syncthreads();
        // stage phi: each thread 12 x-elements
        #pragma unroll
        for (int it = 0; it < (3 * JC * W_IN) / 256; ++it) {
            int n  = it * 256 + tid;
            int kt = n >> 10;              // /(JC*W)
            int j  = (n >> 6) & (JC - 1);
            int w  = n & (W_IN - 1);
            float xv = x[((b * CIN + (j0 + j)) * H_IN + (h + kt)) * W_IN + w];
            float s  = xv * 11.0f;
            int i0 = (int)s;
            i0 = i0 < 0 ? 0 : (i0 > 10 ? 10 : i0);
            float u  = s - (float)i0;
            float um = 1.0f - u;
            float u2 = u * u, u3 = u2 * u;
            const float inv6 = 1.0f / 6.0f;
            float n0 = um * um * um * inv6;
            float n1 = (3.0f * u3 - 6.0f * u2 + 4.0f) * inv6;
            float n2 = (-3.0f * u3 + 3.0f * u2 + 3.0f * u + 1.0f) * inv6;
            float n3 = u3 * inv6;
            ushort* dst = &phi_lds[n << 3];
            int bi = i0 - 3;               // first active basis index
            if ((unsigned)(bi)     < 8u) dst[bi]     = f2bf(n0);
            if ((unsigned)(bi + 1) < 8u) dst[bi + 1] = f2bf(n1);
            if ((unsigned)(bi + 2) < 8u) dst[bi + 2] = f2bf(n2);
            if ((unsigned)(bi + 3) < 8u) dst[bi + 3] = f2bf(n3);
        }
        __syncthreads();
        // GEMM: 36 K-steps x (2 A-frags x 2 B-frags) MFMA 16x16x32
        const v8s* cbv = USE_BT ? (reinterpret_cast<const v8s*>(cb) + j0 * 576) : nullptr;
        #pragma unroll 4
        for (int kk = 0; kk < (JC * 9 * NB) / 32; ++kk) {
            int tap = (kk << 2) + g;       // tap-group this lane-quarter covers
            uint e = lut[tap];
            int philoc = (int)(e & 0xffffu);
            int lt     = (int)((e >> 16) & 3u);
            int w0 = wbase + l15 + lt;
            int w1 = w0 + 16;
            w0 = w0 < 63 ? w0 : 63;        // pad columns read clamped (masked at store)
            w1 = w1 < 63 ? w1 : 63;
            v8s pb0 = *reinterpret_cast<const v8s*>(&phi_lds[philoc + (w0 << 3)]);
            v8s pb1 = *reinterpret_cast<const v8s*>(&phi_lds[philoc + (w1 << 3)]);
            v8s pa0, pa1;
            if constexpr (USE_BT) {
                const v8s* pa = cbv + (tap << 6) + aoff;
                pa0 = pa[0];
                pa1 = pa[16];
            } else {
                int j  = (int)((e >> 20) & 15u);
                int r9 = (int)((e >> 24) & 15u);
                const float* cf = coeff_f + (((aoff * CIN + (j0 + j)) * 9 + r9) << 3);
                #pragma unroll
                for (int z = 0; z < 8; ++z) pa0[z] = (short)f2bf(cf[z]);
                const float* cf2 = cf + (CIN * 9 * NB * 16);
                #pragma unroll
                for (int z = 0; z < 8; ++z) pa1[z] = (short)f2bf(cf2[z]);
            }
            acc00 = __builtin_amdgcn_mfma_f32_16x16x32_bf16(pa0, pb0, acc00, 0, 0, 0);
            acc01 = __builtin_amdgcn_mfma_f32_16x16x32_bf16(pa0, pb1, acc01, 0, 0, 0);
            acc10 = __builtin_amdgcn_mfma_f32_16x16x32_bf16(pa1, pb0, acc10, 0, 0, 0);
            acc11 = __builtin_amdgcn_mfma_f32_16x16x32_bf16(pa1, pb1, acc11, 0, 0, 0);
        }
    }

    // epilogue: D col = lane&15 = w (coalesced), row = g*4+r = o
    const int wc0 = wbase + l15;
    const int wc1 = wc0 + 16;
    #pragma unroll
    for (int i = 0; i < 2; ++i) {
        v4f a0 = (i == 0) ? acc00 : acc10;
        v4f a1 = (i == 0) ? acc01 : acc11;
        int o = obase + i * 16 + (g << 2);
        #pragma unroll
        for (int r = 0; r < 4; ++r) {
            int off = ((b * COUT + o + r) * HO + h) * WO;
            if (wc0 < WO) out[off + wc0] = a0[r];
            if (wc1 < WO) out[off + wc1] = a1[r];
        }
    }
}

extern "C" void kernel_launch(void* const* d_in, const int* in_sizes, int n_in,
                              void* d_out, int out_size, void* d_ws, size_t ws_size,
                              hipStream_t stream) {
    const float* x     = (const float*)d_in[0];
    const float* coeff = (const float*)d_in[1];
    float* out = (float*)d_out;

    const size_t bt_bytes = (size_t)576 * COUT * NB * 2;  // 576 KB
    bool use_bt = ws_size >= bt_bytes;

    if (use_bt) {
        ushort* bt = (ushort*)d_ws;
        prep_coeff_kernel<<<(576 * COUT * NB + 255) / 256, 256, 0, stream>>>(coeff, bt);
        kan_conv_kernel<true><<<dim3(HO, B_N), 256, 0, stream>>>(x, bt, coeff, out);
    } else {
        kan_conv_kernel<false><<<dim3(HO, B_N), 256, 0, stream>>>(x, nullptr, coeff, out);
    }
}

// Round 2
// 59.317 us; speedup vs baseline: 1.8426x; 1.8426x over previous
//
#include <hip/hip_runtime.h>
#include <hip/hip_bf16.h>

// KAN conv: out[b,o,h,w] = sum_{j,k,l,m} phi(x[b,j,h+k,w+l])[m] * coeff[o,j,k,l,m]
// phi = uniform cubic B-spline basis (8 bases, knots = linspace(0,1,12)).
// R2: JC=8 chunks (24KB LDS -> 4 blocks/CU, all 992 blocks resident),
// register-built 16B phi vectors (no zero-fill pass, no u16 scatter conflicts),
// x prefetch for chunk jc+1 issued before the barrier so it rides under GEMM(jc).

typedef short v8s __attribute__((ext_vector_type(8)));
typedef float v4f __attribute__((ext_vector_type(4)));
typedef unsigned long long u64;
typedef u64 v2u64 __attribute__((ext_vector_type(2)));

#define B_N   16
#define CIN   64
#define COUT  64
#define H_IN  64
#define W_IN  64
#define NB    8
#define HO    62
#define WO    62
#define JC    8                 // Cin chunk size
#define NCH   (CIN / JC)        // 8 chunks
#define ELEMS (3 * JC * W_IN)   // 1536 x-elements per chunk
#define EPT   (ELEMS / 256)     // 6 per thread

__device__ __forceinline__ ushort f2bf(float f) {
    // round-to-nearest-even fp32 -> bf16
    uint xu = __float_as_uint(f);
    return (ushort)((xu + 0x7fffu + ((xu >> 16) & 1u)) >> 16);
}

// Rearrange coeff [o][j][k][l][m] f32 -> bt[t=j*9+k*3+l][o][m] bf16 (576 KB)
__global__ void prep_coeff_kernel(const float* __restrict__ coeff, ushort* __restrict__ bt) {
    int n = blockIdx.x * 256 + threadIdx.x;
    if (n >= 576 * COUT * NB) return;
    int m = n & 7;
    int o = (n >> 3) & 63;
    int t = n >> 9;            // j*9 + k*3 + l
    int j = t / 9;
    int r9 = t - j * 9;
    float v = coeff[(((o * CIN + j) * 9 + r9) << 3) + m];
    bt[n] = f2bf(v);
}

template<bool USE_BT>
__global__ __launch_bounds__(256, 4) void kan_conv_kernel(
        const float* __restrict__ x, const ushort* __restrict__ cb,
        const float* __restrict__ coeff_f, float* __restrict__ out) {
    const int h    = blockIdx.x;   // 0..61
    const int b    = blockIdx.y;   // 0..15
    const int tid  = threadIdx.x;
    const int lane = tid & 63;
    const int wv   = tid >> 6;
    const int g    = lane >> 4;    // k-subgroup 0..3
    const int l15  = lane & 15;
    const int obase = (wv >> 1) << 5;  // Cout half: 0 or 32
    const int wbase = (wv & 1) << 5;   // w half:    0 or 32

    // phi_lds[k(3)][j(JC)][w(64)][m(8)] bf16 = 24 KB
    __shared__ __align__(16) ushort phi_lds[3 * JC * W_IN * NB];
    __shared__ uint lut[72];   // tap -> phi base offset | lt<<16 | j<<20 | r9<<24

    if (tid < 72) {
        int tap = tid;
        int j  = tap / 9;
        int r9 = tap - j * 9;
        int kt = r9 / 3;
        int lt = r9 - kt * 3;
        lut[tap] = (uint)(((kt * JC + j) * W_IN) * NB) | ((uint)lt << 16)
                 | ((uint)j << 20) | ((uint)r9 << 24);
    }

    v4f acc00 = {0.f, 0.f, 0.f, 0.f};
    v4f acc01 = acc00, acc10 = acc00, acc11 = acc00;
    const int aoff = obase + l15;

    // prologue: load x for chunk 0
    float xv[EPT];
    #pragma unroll
    for (int it = 0; it < EPT; ++it) {
        int n  = it * 256 + tid;
        int kt = n >> 9;
        int j  = (n >> 6) & (JC - 1);
        int w  = n & (W_IN - 1);
        xv[it] = x[((b * CIN + j) * H_IN + (h + kt)) * W_IN + w];
    }

    for (int jc = 0; jc < NCH; ++jc) {
        // ---- compute phi + single 16B LDS write per element ----
        #pragma unroll
        for (int it = 0; it < EPT; ++it) {
            int n = it * 256 + tid;
            float s  = xv[it] * 11.0f;
            int i0 = (int)s;
            i0 = i0 < 0 ? 0 : (i0 > 10 ? 10 : i0);
            float u  = s - (float)i0;
            float um = 1.0f - u;
            float u2 = u * u, u3 = u2 * u;
            const float inv6 = 1.0f / 6.0f;
            float n0 = um * um * um * inv6;
            float n1 = (3.0f * u3 - 6.0f * u2 + 4.0f) * inv6;
            float n2 = (-3.0f * u3 + 3.0f * u2 + 3.0f * u + 1.0f) * inv6;
            float n3 = u3 * inv6;
            // pack [n0,n1,n2,n3] bf16 into u64, shift to basis start bi=i0-3
            u64 V = (u64)f2bf(n0) | ((u64)f2bf(n1) << 16)
                  | ((u64)f2bf(n2) << 32) | ((u64)f2bf(n3) << 48);
            int bi = i0 - 3;   // in [-3, 7]
            u64 lo = bi < 0 ? (V >> (uint)(-16 * bi))
                   : bi < 4 ? (V << (uint)(16 * bi)) : 0ull;
            u64 hi = bi <= 0 ? 0ull
                   : bi < 4 ? (V >> (uint)(64 - 16 * bi))
                   : (V << (uint)(16 * bi - 64));
            v2u64 pk; pk[0] = lo; pk[1] = hi;
            *reinterpret_cast<v2u64*>(&phi_lds[n << 3]) = pk;
        }
        // ---- prefetch x for chunk jc+1 (in flight across barrier + GEMM) ----
        if (jc + 1 < NCH) {
            int j0n = (jc + 1) * JC;
            #pragma unroll
            for (int it = 0; it < EPT; ++it) {
                int n  = it * 256 + tid;
                int kt = n >> 9;
                int j  = (n >> 6) & (JC - 1);
                int w  = n & (W_IN - 1);
                xv[it] = x[((b * CIN + j0n + j) * H_IN + (h + kt)) * W_IN + w];
            }
        }
        __syncthreads();   // phi ready (also fences lut on first iter)
        // ---- GEMM: 18 K-steps x (2 A-frags x 2 B-frags) MFMA 16x16x32 ----
        const int t0 = jc * JC * 9;    // tap offset into cb
        const v8s* cbv = USE_BT ? reinterpret_cast<const v8s*>(cb) : nullptr;
        #pragma unroll 6
        for (int kk = 0; kk < (JC * 9 * NB) / 32; ++kk) {
            int tap = (kk << 2) + g;
            uint e = lut[tap];
            int philoc = (int)(e & 0xffffu);
            int lt     = (int)((e >> 16) & 3u);
            int w0 = wbase + l15 + lt;
            int w1 = w0 + 16;
            w0 = w0 < 63 ? w0 : 63;     // pad columns clamped (masked at store)
            w1 = w1 < 63 ? w1 : 63;
            v8s pb0 = *reinterpret_cast<const v8s*>(&phi_lds[philoc + (w0 << 3)]);
            v8s pb1 = *reinterpret_cast<const v8s*>(&phi_lds[philoc + (w1 << 3)]);
            v8s pa0, pa1;
            if constexpr (USE_BT) {
                const v8s* pa = cbv + ((t0 + tap) << 6) + aoff;
                pa0 = pa[0];
                pa1 = pa[16];
            } else {
                int j  = (int)((e >> 20) & 15u);
                int r9 = (int)((e >> 24) & 15u);
                const float* cf = coeff_f + (((aoff * CIN + (jc * JC + j)) * 9 + r9) << 3);
                #pragma unroll
                for (int z = 0; z < 8; ++z) pa0[z] = (short)f2bf(cf[z]);
                const float* cf2 = cf + (CIN * 9 * NB * 16);
                #pragma unroll
                for (int z = 0; z < 8; ++z) pa1[z] = (short)f2bf(cf2[z]);
            }
            acc00 = __builtin_amdgcn_mfma_f32_16x16x32_bf16(pa0, pb0, acc00, 0, 0, 0);
            acc01 = __builtin_amdgcn_mfma_f32_16x16x32_bf16(pa0, pb1, acc01, 0, 0, 0);
            acc10 = __builtin_amdgcn_mfma_f32_16x16x32_bf16(pa1, pb0, acc10, 0, 0, 0);
            acc11 = __builtin_amdgcn_mfma_f32_16x16x32_bf16(pa1, pb1, acc11, 0, 0, 0);
        }
        __syncthreads();   // GEMM done before phi overwrite
    }

    // epilogue: D col = lane&15 = w (coalesced), row = g*4+r = o
    const int wc0 = wbase + l15;
    const int wc1 = wc0 + 16;
    #pragma unroll
    for (int i = 0; i < 2; ++i) {
        v4f a0 = (i == 0) ? acc00 : acc10;
        v4f a1 = (i == 0) ? acc01 : acc11;
        int o = obase + i * 16 + (g << 2);
        #pragma unroll
        for (int r = 0; r < 4; ++r) {
            int off = ((b * COUT + o + r) * HO + h) * WO;
            if (wc0 < WO) out[off + wc0] = a0[r];
            if (wc1 < WO) out[off + wc1] = a1[r];
        }
    }
}

extern "C" void kernel_launch(void* const* d_in, const int* in_sizes, int n_in,
                              void* d_out, int out_size, void* d_ws, size_t ws_size,
                              hipStream_t stream) {
    const float* x     = (const float*)d_in[0];
    const float* coeff = (const float*)d_in[1];
    float* out = (float*)d_out;

    const size_t bt_bytes = (size_t)576 * COUT * NB * 2;  // 576 KB
    bool use_bt = ws_size >= bt_bytes;

    if (use_bt) {
        ushort* bt = (ushort*)d_ws;
        prep_coeff_kernel<<<(576 * COUT * NB + 255) / 256, 256, 0, stream>>>(coeff, bt);
        kan_conv_kernel<true><<<dim3(HO, B_N), 256, 0, stream>>>(x, bt, coeff, out);
    } else {
        kan_conv_kernel<false><<<dim3(HO, B_N), 256, 0, stream>>>(x, nullptr, coeff, out);
    }
}